// Round 19
// baseline (49.482 us; speedup 1.0000x reference)
//
#include <hip/hip_runtime.h>

#define NGRAPH 512
#define DF     96
#define DHID   10
#define NCHUNK 512      // sort blocks; echunk = 1563 for E=800000
#define NRANGE 4        // src ranges
#define NBINS  2048     // (graph, src-range) bins: g*4 + r
#define ECHMAX 1600     // LDS staging capacity per chunk (>= echunk)
#define EIDXMAX 2048    // flat per-bin edge capacity (mean ~390)
#define HTHR   1024
#define NTHR   256

// bf16 round-to-nearest-even
static __device__ __forceinline__ unsigned short f2bf(float f) {
    unsigned int u = __float_as_uint(f);
    u = (u + 0x7fffu + ((u >> 16) & 1u)) >> 16;
    return (unsigned short)u;
}
static __device__ __forceinline__ float bf2f(unsigned short s) {
    return __uint_as_float(((unsigned int)s) << 16);
}
static __device__ __forceinline__ unsigned short f2h(float f) {
    _Float16 h = (_Float16)f;
    unsigned short u;
    __builtin_memcpy(&u, &h, 2);
    return u;
}
static __device__ __forceinline__ float h2f(unsigned short u) {
    _Float16 h;
    __builtin_memcpy(&h, &u, 2);
    return (float)h;
}

// ---------------------------------------------------------------------------
// K1 (SORT): x->bf16 conv + per-chunk bin + in-block counting sort into a
// sorted LDS buffer, then coalesced writeout. NCHUNK=512 -> ~24KB LDS ->
// 2 blocks/CU = 32 waves/CU (launch_bounds forces the 64-VGPR budget).
// ---------------------------------------------------------------------------
__global__ __launch_bounds__(HTHR, 8) void sort_kernel(
    const int* __restrict__ edge_index,   // [2E]
    const float* __restrict__ edge_attr,  // [E]
    const int* __restrict__ batch,        // [N] sorted
    const float* __restrict__ x,          // [N*DF]
    int E, int N, int echunk, unsigned int M,
    unsigned short* __restrict__ localpre, // [NCHUNK*NBINS] chunk-major
    unsigned short* __restrict__ xb,       // [N*DF] bf16
    unsigned int* __restrict__ ed)         // [E] lo16 src | hi16 fp16(w)
{
    __shared__ int            lh[NBINS];        // hist, then cursors (8 KB)
    __shared__ unsigned short sbin[ECHMAX];     // per-edge bin       (3.2 KB)
    __shared__ unsigned int   sval[ECHMAX];     // per-edge payload   (6.4 KB)
    __shared__ unsigned int   sval2[ECHMAX];    // sorted payload     (6.4 KB)
    __shared__ int            wvsum[16];

    const int blk = blockIdx.x, t = threadIdx.x;
    const int lane = t & 63, wv = t >> 6;

    // --- x -> bf16 (grid-strided) ---
    const int nf4 = N * DF / 4;
    for (int i = blk * HTHR + t; i < nf4; i += NCHUNK * HTHR) {
        const float4 v = ((const float4*)x)[i];
        ushort4 o;
        o.x = f2bf(v.x); o.y = f2bf(v.y); o.z = f2bf(v.z); o.w = f2bf(v.w);
        ((ushort4*)xb)[i] = o;
    }

    for (int i = t; i < NBINS; i += HTHR) lh[i] = 0;
    __syncthreads();

    // --- bin + payload + LDS hist ---
    const int* __restrict__ src = edge_index;
    const int* __restrict__ dst = edge_index + E;
    const int lo = blk * echunk;
    const int hi = min(E, lo + echunk);
    for (int e = lo + t; e < hi; e += HTHR) {
        const int g = batch[dst[e]];
        const int r = (int)__umulhi((unsigned int)src[e], M);   // 0..3
        const int b = (g << 2) | r;
        sbin[e - lo] = (unsigned short)b;
        sval[e - lo] = (unsigned int)(src[e] & 0xffff)
                     | ((unsigned int)f2h(edge_attr[e]) << 16);
        atomicAdd(&lh[b], 1);
    }
    __syncthreads();

    // --- block-wide exclusive scan of lh[2048], 2 bins/thread ---
    const int v0 = lh[2 * t], v1 = lh[2 * t + 1];
    const int s = v0 + v1;
    int p = s;
#pragma unroll
    for (int d = 1; d < 64; d <<= 1) {
        const int u = __shfl_up(p, d, 64);
        if (lane >= d) p += u;
    }
    if (lane == 63) wvsum[wv] = p;
    __syncthreads();
    int add = 0;
#pragma unroll
    for (int i = 0; i < 16; ++i) if (i < wv) add += wvsum[i];
    const int ex = p - s + add;                  // block-exclusive prefix

    ushort2 o;                                   // export coalesced u16x2
    o.x = (unsigned short)ex;
    o.y = (unsigned short)(ex + v0);
    ((ushort2*)(localpre + (size_t)blk * NBINS))[t] = o;
    __syncthreads();                             // all lh reads done
    lh[2 * t]     = ex;                          // reuse hist as cursors
    lh[2 * t + 1] = ex + v0;
    __syncthreads();

    // --- place into sorted LDS buffer ---
    const int cnt = hi - lo;
    for (int i = t; i < cnt; i += HTHR) {
        const int ppos = atomicAdd(&lh[sbin[i]], 1);
        sval2[ppos] = sval[i];
    }
    __syncthreads();

    // --- coalesced writeout of the private slab ---
    for (int j = t; j < cnt; j += HTHR)
        ed[lo + j] = sval2[j];
}

// ---------------------------------------------------------------------------
// K2 (AGGREGATE): per-bin gather via flat LDS position table. Thread t owns
// chunks 2t, 2t+1 (cum[] stays monotonic). blockIdx=bin=g*4+r: XCD k only
// touches src-range k mod 4, whose bf16 slice (2.4 MB) stays XCD-L2-local.
// ---------------------------------------------------------------------------
__global__ __launch_bounds__(NTHR) void aggregate_kernel(
    const unsigned int* __restrict__ ed,
    const unsigned short* __restrict__ localpre,  // [NCHUNK*NBINS]
    const unsigned short* __restrict__ xb,
    int E, int echunk,
    float* __restrict__ partial)          // [NBINS*DF]
{
    __shared__ int   eidx[EIDXMAX];       // flat ed positions (8 KB)
    __shared__ int   cum[NCHUNK];
    __shared__ int   sstart[NCHUNK];
    __shared__ int   wt[4];
    __shared__ int   sT;
    __shared__ float sh4[4][DF];

    const int bin = blockIdx.x, t = threadIdx.x;
    const int lane = t & 63, wv = t >> 6;

    // --- preamble: segments of chunks 2t, 2t+1 + scan of counts ---
    const int c0 = 2 * t, c1 = 2 * t + 1;
    const int pb0 = (int)localpre[(size_t)c0 * NBINS + bin];
    const int pe0 = (bin < NBINS - 1)
                  ? (int)localpre[(size_t)c0 * NBINS + bin + 1]
                  : (min(echunk, E - c0 * echunk));
    const int pb1 = (int)localpre[(size_t)c1 * NBINS + bin];
    const int pe1 = (bin < NBINS - 1)
                  ? (int)localpre[(size_t)c1 * NBINS + bin + 1]
                  : (min(echunk, E - c1 * echunk));
    const int cnt0 = pe0 - pb0;
    const int cnt1 = pe1 - pb1;
    const int st0 = c0 * echunk + pb0;
    const int st1 = c1 * echunk + pb1;
    sstart[c0] = st0;
    sstart[c1] = st1;

    const int s = cnt0 + cnt1;
    int p = s;
#pragma unroll
    for (int d = 1; d < 64; d <<= 1) {
        const int u = __shfl_up(p, d, 64);
        if (lane >= d) p += u;
    }
    if (lane == 63) wt[wv] = p;
    __syncthreads();
    int add = 0;
#pragma unroll
    for (int i = 0; i < 4; ++i) if (i < wv) add += wt[i];
    const int incl = p + add;
    const int base0 = incl - s;                  // start for chunk c0
    cum[c0] = base0;
    cum[c1] = base0 + cnt0;
    if (t == NTHR - 1) sT = incl;
    __syncthreads();
    const int T = sT;

    // --- fill flat position table (~0-3 writes/thread) ---
    for (int j = 0; j < cnt0; ++j) {
        const int idx = base0 + j;
        if (idx < EIDXMAX) eidx[idx] = st0 + j;
    }
    for (int j = 0; j < cnt1; ++j) {
        const int idx = base0 + cnt0 + j;
        if (idx < EIDXMAX) eidx[idx] = st1 + j;
    }
    __syncthreads();

    const int eg = lane >> 3;                     // 8 edge-slots / wave
    const int fc = lane & 7;                      // 8B feature chunk lane
    float acc[12];
#pragma unroll
    for (int i = 0; i < 12; ++i) acc[i] = 0.f;

    const int Tc = min(T, EIDXMAX);
    for (int k = wv * 8 + eg; k < Tc; k += 32) {
        const unsigned int sw = ed[eidx[k]];
        const float w = h2f((unsigned short)(sw >> 16));
        const ushort4* __restrict__ row =
            (const ushort4*)xb + (size_t)(sw & 0xffffu) * 24;
#pragma unroll
        for (int c = 0; c < 3; ++c) {
            const ushort4 vv = row[fc + c * 8];
            acc[c * 4 + 0] += w * bf2f(vv.x);
            acc[c * 4 + 1] += w * bf2f(vv.y);
            acc[c * 4 + 2] += w * bf2f(vv.z);
            acc[c * 4 + 3] += w * bf2f(vv.w);
        }
    }
    // statistically-never overflow fallback: bsearch over cum[] (monotonic)
    for (int k = EIDXMAX + wv * 8 + eg; k < T; k += 32) {
        int lo2 = 0, hi2 = NCHUNK - 1;
#pragma unroll
        for (int it = 0; it < 9; ++it) {
            const int m = (lo2 + hi2 + 1) >> 1;
            if (cum[m] <= k) lo2 = m; else hi2 = m - 1;
        }
        const unsigned int sw = ed[sstart[lo2] + (k - cum[lo2])];
        const float w = h2f((unsigned short)(sw >> 16));
        const ushort4* __restrict__ row =
            (const ushort4*)xb + (size_t)(sw & 0xffffu) * 24;
#pragma unroll
        for (int c = 0; c < 3; ++c) {
            const ushort4 vv = row[fc + c * 8];
            acc[c * 4 + 0] += w * bf2f(vv.x);
            acc[c * 4 + 1] += w * bf2f(vv.y);
            acc[c * 4 + 2] += w * bf2f(vv.z);
            acc[c * 4 + 3] += w * bf2f(vv.w);
        }
    }

#pragma unroll
    for (int m = 8; m <= 32; m <<= 1) {
#pragma unroll
        for (int i = 0; i < 12; ++i) acc[i] += __shfl_xor(acc[i], m, 64);
    }
    if (eg == 0) {
#pragma unroll
        for (int c = 0; c < 3; ++c)
#pragma unroll
            for (int k2 = 0; k2 < 4; ++k2)
                sh4[wv][c * 32 + fc * 4 + k2] = acc[c * 4 + k2];
    }
    __syncthreads();
    if (t < DF)
        partial[(size_t)bin * DF + t] =
            sh4[0][t] + sh4[1][t] + sh4[2][t] + sh4[3][t];
}

// ---------------------------------------------------------------------------
// K3 (FINISH): reduce 4 range-partials + mean (bsearch counts) + MLP head.
// ---------------------------------------------------------------------------
__global__ __launch_bounds__(128) void finish_kernel(
    const float* __restrict__ partial,    // [NBINS*DF]
    const int* __restrict__ batch,        // [N] sorted
    int N,
    const float* __restrict__ W1,
    const float* __restrict__ b1,
    const float* __restrict__ W2,
    const float* __restrict__ b2,
    float* __restrict__ out)
{
    __shared__ float sW1[DF * DHID];
    __shared__ float fin[DF];
    __shared__ int   scnt[2];
    const int g = blockIdx.x, t = threadIdx.x;

    if (t < 2) {
        const int key = g + t;
        int lo = 0, hi = N;
        while (lo < hi) {
            const int m = (lo + hi) >> 1;
            if (batch[m] < key) lo = m + 1; else hi = m;
        }
        scnt[t] = lo;
    }
    for (int i = t; i < DF * DHID; i += 128) sW1[i] = W1[i];
    __syncthreads();

    if (t < DF) {
        float s = 0.f;
#pragma unroll
        for (int r = 0; r < NRANGE; ++r)
            s += partial[(size_t)((g << 2) | r) * DF + t];
        const int cnt = scnt[1] - scnt[0];
        fin[t] = fmaxf(s / fmaxf((float)cnt, 1.f), 0.f);
    }
    __syncthreads();
    if (t < 16) {
        float v = 0.f;
        if (t < DHID) {
            float h = b1[t];
            for (int f = 0; f < DF; ++f) h += fin[f] * sW1[f * DHID + t];
            v = fmaxf(h, 0.f) * W2[t];
        }
#pragma unroll
        for (int m = 1; m < 16; m <<= 1) v += __shfl_xor(v, m, 16);
        if (t == 0) out[g] = v + b2[0];
    }
}

// ---------------------------------------------------------------------------
extern "C" void kernel_launch(void* const* d_in, const int* in_sizes, int n_in,
                              void* d_out, int out_size, void* d_ws, size_t ws_size,
                              hipStream_t stream) {
    const float* x          = (const float*)d_in[0];
    const int*   edge_index = (const int*)  d_in[1];
    const float* edge_attr  = (const float*)d_in[2];
    const int*   batch      = (const int*)  d_in[3];
    const float* W1         = (const float*)d_in[4];
    const float* b1         = (const float*)d_in[5];
    const float* W2         = (const float*)d_in[6];
    const float* b2         = (const float*)d_in[7];

    const int E = in_sizes[1] / 2;   // 800000
    const int N = in_sizes[3];       // 50000 (< 65536: src fits u16)
    const int echunk = (E + NCHUNK - 1) / NCHUNK;   // 1563 (<= ECHMAX)
    const unsigned int RDIV = (unsigned int)((N + NRANGE - 1) / NRANGE);
    const unsigned int M = (unsigned int)((0x100000000ULL + RDIV - 1) / RDIV);

    // workspace: ed 4E | xb 2*N*DF | localpre 2MB | partial 768KB
    char* ws = (char*)d_ws;
    unsigned int*   ed = (unsigned int*)ws;                          // 4E
    unsigned short* xb = (unsigned short*)(ws + (size_t)4 * E);      // 2*N*DF
    char* tail = ws + (size_t)4 * E + (size_t)2 * N * DF;
    tail = (char*)(((size_t)tail + 255) & ~(size_t)255);
    unsigned short* localpre = (unsigned short*)tail;                // 2 MB
    float*          partial  = (float*)(localpre + (size_t)NCHUNK * NBINS);

    sort_kernel<<<NCHUNK, HTHR, 0, stream>>>(edge_index, edge_attr, batch, x,
                                             E, N, echunk, M,
                                             localpre, xb, ed);
    aggregate_kernel<<<NBINS, NTHR, 0, stream>>>(ed, localpre, xb,
                                                 E, echunk, partial);
    finish_kernel<<<NGRAPH, 128, 0, stream>>>(partial, batch, N,
                                              W1, b1, W2, b2, (float*)d_out);
}

// Round 20
// 45.577 us; speedup vs baseline: 1.0857x; 1.0857x over previous
//
#include <hip/hip_runtime.h>

#define NGRAPH 512
#define DF     96
#define DHID   10
#define NCHUNK 256      // sort blocks; echunk = 3125 for E=800000
#define NRANGE 4        // src ranges
#define NBINS  2048     // (graph, src-range) bins: g*4 + r
#define ECHMAX 3200     // LDS staging capacity per chunk (>= echunk)
#define EIDXMAX 2048    // flat per-bin edge capacity (mean ~390, max ~500)
#define HTHR   1024
#define NTHR   256

// bf16 round-to-nearest-even
static __device__ __forceinline__ unsigned short f2bf(float f) {
    unsigned int u = __float_as_uint(f);
    u = (u + 0x7fffu + ((u >> 16) & 1u)) >> 16;
    return (unsigned short)u;
}
static __device__ __forceinline__ float bf2f(unsigned short s) {
    return __uint_as_float(((unsigned int)s) << 16);
}
static __device__ __forceinline__ unsigned short f2h(float f) {
    _Float16 h = (_Float16)f;
    unsigned short u;
    __builtin_memcpy(&u, &h, 2);
    return u;
}
static __device__ __forceinline__ float h2f(unsigned short u) {
    _Float16 h;
    __builtin_memcpy(&h, &u, 2);
    return (float)h;
}

// ---------------------------------------------------------------------------
// K1 (SORT): x->bf16 conv + per-chunk bin + in-block counting sort into a
// sorted LDS buffer, then fully coalesced writeout of the chunk-private slab.
// ---------------------------------------------------------------------------
__global__ __launch_bounds__(HTHR) void sort_kernel(
    const int* __restrict__ edge_index,   // [2E]
    const float* __restrict__ edge_attr,  // [E]
    const int* __restrict__ batch,        // [N] sorted
    const float* __restrict__ x,          // [N*DF]
    int E, int N, int echunk, unsigned int M,
    unsigned short* __restrict__ localpre, // [NCHUNK*NBINS] chunk-major
    unsigned short* __restrict__ xb,       // [N*DF] bf16
    unsigned int* __restrict__ ed)         // [E] lo16 src | hi16 fp16(w)
{
    __shared__ int            lh[NBINS];        // hist, then cursors (8 KB)
    __shared__ unsigned short sbin[ECHMAX];     // per-edge bin       (6.4 KB)
    __shared__ unsigned int   sval[ECHMAX];     // per-edge payload  (12.8 KB)
    __shared__ unsigned int   sval2[ECHMAX];    // sorted payload    (12.8 KB)
    __shared__ int            wvsum[16];

    const int blk = blockIdx.x, t = threadIdx.x;
    const int lane = t & 63, wv = t >> 6;

    // --- x -> bf16 (grid-strided) ---
    const int nf4 = N * DF / 4;
    for (int i = blk * HTHR + t; i < nf4; i += NCHUNK * HTHR) {
        const float4 v = ((const float4*)x)[i];
        ushort4 o;
        o.x = f2bf(v.x); o.y = f2bf(v.y); o.z = f2bf(v.z); o.w = f2bf(v.w);
        ((ushort4*)xb)[i] = o;
    }

    for (int i = t; i < NBINS; i += HTHR) lh[i] = 0;
    __syncthreads();

    // --- bin + payload + LDS hist ---
    const int* __restrict__ src = edge_index;
    const int* __restrict__ dst = edge_index + E;
    const int lo = blk * echunk;
    const int hi = min(E, lo + echunk);
    for (int e = lo + t; e < hi; e += HTHR) {
        const int g = batch[dst[e]];
        const int r = (int)__umulhi((unsigned int)src[e], M);   // 0..3
        const int b = (g << 2) | r;
        sbin[e - lo] = (unsigned short)b;
        sval[e - lo] = (unsigned int)(src[e] & 0xffff)
                     | ((unsigned int)f2h(edge_attr[e]) << 16);
        atomicAdd(&lh[b], 1);
    }
    __syncthreads();

    // --- block-wide exclusive scan of lh[2048], 2 bins/thread ---
    const int v0 = lh[2 * t], v1 = lh[2 * t + 1];
    const int s = v0 + v1;
    int p = s;
#pragma unroll
    for (int d = 1; d < 64; d <<= 1) {
        const int u = __shfl_up(p, d, 64);
        if (lane >= d) p += u;
    }
    if (lane == 63) wvsum[wv] = p;
    __syncthreads();
    int add = 0;
#pragma unroll
    for (int i = 0; i < 16; ++i) if (i < wv) add += wvsum[i];
    const int ex = p - s + add;                  // block-exclusive prefix

    ushort2 o;                                   // export coalesced u16x2
    o.x = (unsigned short)ex;
    o.y = (unsigned short)(ex + v0);
    ((ushort2*)(localpre + (size_t)blk * NBINS))[t] = o;
    __syncthreads();                             // all lh reads done
    lh[2 * t]     = ex;                          // reuse hist as cursors
    lh[2 * t + 1] = ex + v0;
    __syncthreads();

    // --- place into sorted LDS buffer ---
    const int cnt = hi - lo;
    for (int i = t; i < cnt; i += HTHR) {
        const int ppos = atomicAdd(&lh[sbin[i]], 1);
        sval2[ppos] = sval[i];
    }
    __syncthreads();

    // --- coalesced writeout of the private slab ---
    for (int j = t; j < cnt; j += HTHR)
        ed[lo + j] = sval2[j];
}

// ---------------------------------------------------------------------------
// K2 (AGGREGATE): per-bin gather via flat LDS position table (no per-edge
// search, all edge-slot lanes dense). blockIdx=bin=g*4+r: bin mod 8 is
// {r, r+4} -> XCD k only touches src-range k mod 4, whose bf16 slice
// (2.4 MB) stays XCD-L2-local.
// ---------------------------------------------------------------------------
__global__ __launch_bounds__(NTHR) void aggregate_kernel(
    const unsigned int* __restrict__ ed,
    const unsigned short* __restrict__ localpre,  // [NCHUNK*NBINS]
    const unsigned short* __restrict__ xb,
    int E, int echunk,
    float* __restrict__ partial)          // [NBINS*DF]
{
    __shared__ int   eidx[EIDXMAX];       // flat ed positions (8 KB)
    __shared__ int   cum[NCHUNK];
    __shared__ int   sstart[NCHUNK];
    __shared__ int   wt[4];
    __shared__ int   sT;
    __shared__ float sh4[4][DF];

    const int bin = blockIdx.x, t = threadIdx.x;
    const int lane = t & 63, wv = t >> 6;

    // --- preamble: segment of chunk t + exclusive scan of counts ---
    const int pb = (int)localpre[(size_t)t * NBINS + bin];
    const int pe = (bin < NBINS - 1)
                 ? (int)localpre[(size_t)t * NBINS + bin + 1]
                 : (min(echunk, E - t * echunk));
    const int cnt = pe - pb;
    const int start = t * echunk + pb;
    sstart[t] = start;

    int p = cnt;
#pragma unroll
    for (int d = 1; d < 64; d <<= 1) {
        const int u = __shfl_up(p, d, 64);
        if (lane >= d) p += u;
    }
    if (lane == 63) wt[wv] = p;
    __syncthreads();
    int add = 0;
#pragma unroll
    for (int i = 0; i < 4; ++i) if (i < wv) add += wt[i];
    const int incl = p + add;
    const int base0 = incl - cnt;
    cum[t] = base0;
    if (t == NTHR - 1) sT = incl;
    __syncthreads();
    const int T = sT;

    // --- fill flat position table (~0-3 writes/thread) ---
    for (int j = 0; j < cnt; ++j) {
        const int idx = base0 + j;
        if (idx < EIDXMAX) eidx[idx] = start + j;
    }
    __syncthreads();

    const int eg = lane >> 3;                     // 8 edge-slots / wave
    const int fc = lane & 7;                      // 8B feature chunk lane
    float acc[12];
#pragma unroll
    for (int i = 0; i < 12; ++i) acc[i] = 0.f;

    const int Tc = min(T, EIDXMAX);
    for (int k = wv * 8 + eg; k < Tc; k += 32) {
        const unsigned int sw = ed[eidx[k]];
        const float w = h2f((unsigned short)(sw >> 16));
        const ushort4* __restrict__ row =
            (const ushort4*)xb + (size_t)(sw & 0xffffu) * 24;
#pragma unroll
        for (int c = 0; c < 3; ++c) {
            const ushort4 vv = row[fc + c * 8];
            acc[c * 4 + 0] += w * bf2f(vv.x);
            acc[c * 4 + 1] += w * bf2f(vv.y);
            acc[c * 4 + 2] += w * bf2f(vv.z);
            acc[c * 4 + 3] += w * bf2f(vv.w);
        }
    }
    // statistically-never overflow fallback: bsearch over cum[]
    for (int k = EIDXMAX + wv * 8 + eg; k < T; k += 32) {
        int lo2 = 0, hi2 = NCHUNK - 1;
#pragma unroll
        for (int it = 0; it < 8; ++it) {
            const int m = (lo2 + hi2 + 1) >> 1;
            if (cum[m] <= k) lo2 = m; else hi2 = m - 1;
        }
        const unsigned int sw = ed[sstart[lo2] + (k - cum[lo2])];
        const float w = h2f((unsigned short)(sw >> 16));
        const ushort4* __restrict__ row =
            (const ushort4*)xb + (size_t)(sw & 0xffffu) * 24;
#pragma unroll
        for (int c = 0; c < 3; ++c) {
            const ushort4 vv = row[fc + c * 8];
            acc[c * 4 + 0] += w * bf2f(vv.x);
            acc[c * 4 + 1] += w * bf2f(vv.y);
            acc[c * 4 + 2] += w * bf2f(vv.z);
            acc[c * 4 + 3] += w * bf2f(vv.w);
        }
    }

#pragma unroll
    for (int m = 8; m <= 32; m <<= 1) {
#pragma unroll
        for (int i = 0; i < 12; ++i) acc[i] += __shfl_xor(acc[i], m, 64);
    }
    if (eg == 0) {
#pragma unroll
        for (int c = 0; c < 3; ++c)
#pragma unroll
            for (int k2 = 0; k2 < 4; ++k2)
                sh4[wv][c * 32 + fc * 4 + k2] = acc[c * 4 + k2];
    }
    __syncthreads();
    if (t < DF)
        partial[(size_t)bin * DF + t] =
            sh4[0][t] + sh4[1][t] + sh4[2][t] + sh4[3][t];
}

// ---------------------------------------------------------------------------
// K3 (FINISH): reduce 4 range-partials + mean (bsearch counts) + MLP head.
// ---------------------------------------------------------------------------
__global__ __launch_bounds__(128) void finish_kernel(
    const float* __restrict__ partial,    // [NBINS*DF]
    const int* __restrict__ batch,        // [N] sorted
    int N,
    const float* __restrict__ W1,
    const float* __restrict__ b1,
    const float* __restrict__ W2,
    const float* __restrict__ b2,
    float* __restrict__ out)
{
    __shared__ float sW1[DF * DHID];
    __shared__ float fin[DF];
    __shared__ int   scnt[2];
    const int g = blockIdx.x, t = threadIdx.x;

    if (t < 2) {
        const int key = g + t;
        int lo = 0, hi = N;
        while (lo < hi) {
            const int m = (lo + hi) >> 1;
            if (batch[m] < key) lo = m + 1; else hi = m;
        }
        scnt[t] = lo;
    }
    for (int i = t; i < DF * DHID; i += 128) sW1[i] = W1[i];
    __syncthreads();

    if (t < DF) {
        float s = 0.f;
#pragma unroll
        for (int r = 0; r < NRANGE; ++r)
            s += partial[(size_t)((g << 2) | r) * DF + t];
        const int cnt = scnt[1] - scnt[0];
        fin[t] = fmaxf(s / fmaxf((float)cnt, 1.f), 0.f);
    }
    __syncthreads();
    if (t < 16) {
        float v = 0.f;
        if (t < DHID) {
            float h = b1[t];
            for (int f = 0; f < DF; ++f) h += fin[f] * sW1[f * DHID + t];
            v = fmaxf(h, 0.f) * W2[t];
        }
#pragma unroll
        for (int m = 1; m < 16; m <<= 1) v += __shfl_xor(v, m, 16);
        if (t == 0) out[g] = v + b2[0];
    }
}

// ---------------------------------------------------------------------------
extern "C" void kernel_launch(void* const* d_in, const int* in_sizes, int n_in,
                              void* d_out, int out_size, void* d_ws, size_t ws_size,
                              hipStream_t stream) {
    const float* x          = (const float*)d_in[0];
    const int*   edge_index = (const int*)  d_in[1];
    const float* edge_attr  = (const float*)d_in[2];
    const int*   batch      = (const int*)  d_in[3];
    const float* W1         = (const float*)d_in[4];
    const float* b1         = (const float*)d_in[5];
    const float* W2         = (const float*)d_in[6];
    const float* b2         = (const float*)d_in[7];

    const int E = in_sizes[1] / 2;   // 800000
    const int N = in_sizes[3];       // 50000 (< 65536: src fits u16)
    const int echunk = (E + NCHUNK - 1) / NCHUNK;   // 3125 (<= ECHMAX)
    const unsigned int RDIV = (unsigned int)((N + NRANGE - 1) / NRANGE);
    const unsigned int M = (unsigned int)((0x100000000ULL + RDIV - 1) / RDIV);

    // workspace: ed 4E | xb 2*N*DF | localpre 1MB | partial 768KB
    char* ws = (char*)d_ws;
    unsigned int*   ed = (unsigned int*)ws;                          // 4E
    unsigned short* xb = (unsigned short*)(ws + (size_t)4 * E);      // 2*N*DF
    char* tail = ws + (size_t)4 * E + (size_t)2 * N * DF;
    tail = (char*)(((size_t)tail + 255) & ~(size_t)255);
    unsigned short* localpre = (unsigned short*)tail;                // 1 MB
    float*          partial  = (float*)(localpre + (size_t)NCHUNK * NBINS);

    sort_kernel<<<NCHUNK, HTHR, 0, stream>>>(edge_index, edge_attr, batch, x,
                                             E, N, echunk, M,
                                             localpre, xb, ed);
    aggregate_kernel<<<NBINS, NTHR, 0, stream>>>(ed, localpre, xb,
                                                 E, echunk, partial);
    finish_kernel<<<NGRAPH, 128, 0, stream>>>(partial, batch, N,
                                              W1, b1, W2, b2, (float*)d_out);
}